// Round 9
// baseline (24559.468 us; speedup 1.0000x reference)
//
#include <hip/hip_runtime.h>
#include <hip/hip_bf16.h>

#define SEQ   512
#define BATCH 128
#define XD    256
#define PHID  512
#define RD    256
#define OUTD  256
#define NG    8      // row-groups of 16 rows; one s-block each (intra-block pipeline)
#define NOB   16     // o-blocks, 2 per group (128 out-cols each), lag via LLC ring
#define RING  16

typedef __attribute__((ext_vector_type(8))) short short8;
typedef __attribute__((ext_vector_type(4))) float floatx4;

#define MFMA(a, b, c) __builtin_amdgcn_mfma_f32_16x16x32_bf16((a), (b), (c), 0, 0, 0)

__device__ inline short8 ldg8(const __hip_bfloat16* p) {
    return *reinterpret_cast<const short8*>(p);
}
// agent-coherent 16B load from LLC (verified r2/r4/r6): for o-blocks' phi reads
__device__ inline void ldcc(short8& d, const __hip_bfloat16* p) {
    asm volatile("global_load_dwordx4 %0, %1, off sc1"
                 : "=v"(d) : "v"(p) : "memory");
}
// agent-coherent 2B store: write-through to LLC (never dirties L2)
__device__ inline void stcc16(__hip_bfloat16* p, __hip_bfloat16 v) {
    const short sv = __builtin_bit_cast(short, v);
    asm volatile("global_store_short %0, %1, off sc1"
                 :: "v"(p), "v"(sv) : "memory");
}
__device__ inline int flagld(const int* p) {
    return __hip_atomic_load(p, __ATOMIC_RELAXED, __HIP_MEMORY_SCOPE_AGENT);
}
__device__ inline void flag_sc1(int* p, int v) {
    asm volatile("global_store_dword %0, %1, off sc1"
                 :: "v"(p), "v"(v) : "memory");
}

__global__ void convert_f32_bf16(const float* __restrict__ s, __hip_bfloat16* __restrict__ d) {
    const int gid = blockIdx.x * blockDim.x + threadIdx.x;   // grid covers N/4 exactly
    const float4 v = reinterpret_cast<const float4*>(s)[gid];
    __hip_bfloat16* p = d + 4 * (size_t)gid;
    p[0] = __float2bfloat16(v.x); p[1] = __float2bfloat16(v.y);
    p[2] = __float2bfloat16(v.z); p[3] = __float2bfloat16(v.w);
}

// ROW-PARTITIONED pipeline: batch rows are fully independent in this recurrence,
// so each 16-row group runs on ONE block with r/phi in LDS (__syncthreads only —
// no LLC hop on the critical path). Roles:
//   bid 0..7  : s-blocks, 1024 thr (16 waves). Per step: phi = relu(x@W2x^T +
//               r@W2r^T + b2) [wave w owns 32 phi cols]; s_a = alpha*s_a +
//               (1-alpha)*phi@W1_a^T [wave w owns 16 r cols]; r_{t+1} in LDS.
//               phi also streamed to an LLC ring for the o-blocks (off-path).
//   bid 8..23 : o-blocks, 8 waves (512 thr used). o_a accumulates mu_a@Wo_a^T
//               from the phi ring; lags freely; writes its 128 out-cols at end.
// Cross-block protocol (phi->o only): sc1 write-through + vmcnt(0) + sc1 flag;
// consumer ballot-spin + sc1 loads. (Verified rounds 2/4/6.)
__global__ void __launch_bounds__(1024) sru_rows(
    const float* __restrict__ b1, const float* __restrict__ b2,
    const float* __restrict__ bo,
    const __hip_bfloat16* __restrict__ xbf,
    const __hip_bfloat16* __restrict__ W1b,   // 256x2048 bf16 row-major
    const __hip_bfloat16* __restrict__ W2b,   // 512x512  bf16 row-major (x|r)
    const __hip_bfloat16* __restrict__ Wob,   // 256x2048 bf16 row-major
    __hip_bfloat16* __restrict__ phib,        // [NG][RING][16][512]
    float* __restrict__ out, int* __restrict__ ctrl)
{
    __shared__ __hip_bfloat16 r_lds[16 * 256];    // XOR-swizzled (elem ^ (row&7)<<3)
    __shared__ __hip_bfloat16 p_lds[16 * 512];
    const int bid  = blockIdx.x;
    const int tid  = threadIdx.x;
    const int wave = tid >> 6;
    const int lane = tid & 63;
    const int quad = lane >> 4;
    const int lrow = lane & 15;
    int* pfl = ctrl;             // (g*16 + w)*16
    int* ofl = ctrl + 4096;      // (ob*8 + w)*16  [ob = 2g+half -> idx 16g+8h+w]
    const float pre[4]  = {0.f, 1.f, 9.f, 99.f};    // alpha/(1-alpha)
    const float post[4] = {1.f, 0.5f, 0.1f, 0.01f}; // (1-alpha)

    if (bid < NG) {
        // ================= s-block: rows g*16..g*16+15 =================
        const int g  = bid;
        const int jp = wave * 32;    // phi cols [jp, jp+32)
        const int js = wave * 16;    // r / s cols [js, js+16)
        const float b1v = b1[js + lrow];
        const float b2v0 = b2[jp + lrow];
        const float b2v1 = b2[jp + 16 + lrow];
        floatx4 s4[4] = {};
        // r_0 = relu(b1) (s-state starts at 0)
        #pragma unroll
        for (int i = 0; i < 4; ++i) {
            const int row = quad * 4 + i;
            r_lds[(row * 256 + js + lrow) ^ ((row & 7) << 3)] =
                __float2bfloat16(fmaxf(b1v, 0.f));
        }
        #pragma unroll 1
        for (int t = 0; t < SEQ; ++t) {
            __syncthreads();                       // r_t ready; p_lds free
            // ring gate every 8 steps: o must have passed t-8 (16 slots, 8-step window)
            if ((t & 7) == 0) {
                int guard = 0;
                while (true) {
                    const bool nr = (lane < 16) &&
                        (flagld(&ofl[(g * 16 + lane) * 16]) < t - 8);
                    if (__ballot(nr) == 0) break;
                    if (++guard > 16384) break;
                }
            }
            // ---- phi-phase: pacc = x@W2x^T + r@W2r^T ----
            floatx4 pacc[2] = {};
            const __hip_bfloat16* xr = xbf + ((size_t)t * BATCH + g * 16) * XD;
            #pragma unroll 4
            for (int ks = 0; ks < 8; ++ks) {
                const short8 ax = ldg8(xr + lrow * XD + ks * 32 + 8 * quad);
                const short8 ar = ldg8(&r_lds[(lrow * 256 + ks * 32 + 8 * quad)
                                              ^ ((lrow & 7) << 3)]);
                #pragma unroll
                for (int j2 = 0; j2 < 2; ++j2) {
                    const short8 bx = ldg8(W2b + (jp + j2 * 16 + lrow) * 512
                                               + ks * 32 + 8 * quad);
                    const short8 br = ldg8(W2b + (jp + j2 * 16 + lrow) * 512
                                               + 256 + ks * 32 + 8 * quad);
                    pacc[j2] = MFMA(ax, bx, pacc[j2]);
                    pacc[j2] = MFMA(ar, br, pacc[j2]);
                }
            }
            // epilogue: relu -> LDS (for s-phase) + LLC ring (for o-blocks)
            __hip_bfloat16* pb = phib + ((size_t)(g * RING + (t & (RING - 1))) * 16) * 512;
            #pragma unroll
            for (int j2 = 0; j2 < 2; ++j2)
                #pragma unroll
                for (int i = 0; i < 4; ++i) {
                    const int row = quad * 4 + i;
                    const int col = jp + j2 * 16 + lrow;
                    const float v = pacc[j2][i] + (j2 ? b2v1 : b2v0);
                    const __hip_bfloat16 ph = __float2bfloat16(fmaxf(v, 0.f));
                    p_lds[(row * 512 + col) ^ ((row & 7) << 3)] = ph;
                    stcc16(pb + row * 512 + col, ph);
                }
            __syncthreads();                       // phi_t resident in LDS
            // ---- s-phase: s_a = alpha*s_a + (1-alpha)*phi@W1_a^T ----
            #pragma unroll
            for (int a = 0; a < 4; ++a) s4[a] *= pre[a];
            #pragma unroll 2
            for (int ks = 0; ks < 16; ++ks) {
                const short8 ap = ldg8(&p_lds[(lrow * 512 + ks * 32 + 8 * quad)
                                              ^ ((lrow & 7) << 3)]);
                #pragma unroll
                for (int a = 0; a < 4; ++a) {
                    const short8 bw = ldg8(W1b + (js + lrow) * 2048 + a * 512
                                               + ks * 32 + 8 * quad);
                    s4[a] = MFMA(ap, bw, s4[a]);
                }
            }
            #pragma unroll
            for (int a = 0; a < 4; ++a) s4[a] *= post[a];
            // r_{t+1} = relu(sum_a s_a + b1)
            #pragma unroll
            for (int i = 0; i < 4; ++i) {
                const int row = quad * 4 + i;
                const float rv = s4[0][i] + s4[1][i] + s4[2][i] + s4[3][i] + b1v;
                r_lds[(row * 256 + js + lrow) ^ ((row & 7) << 3)] =
                    __float2bfloat16(fmaxf(rv, 0.f));
            }
            // post per-wave flag: by now the weight loads issued AFTER the phi
            // stores have completed (FIFO vmcnt) -> stores are at LLC; the
            // explicit drain is effectively free.
            asm volatile("s_waitcnt vmcnt(0)" ::: "memory");
            if (lane == 0) flag_sc1(&pfl[(g * 16 + wave) * 16], t + 1);
        }
    } else {
        // ================= o-block: group g, half h -> 128 out-cols =========
        const int ob = bid - NG;
        if (wave >= 8) return;                    // 512 active threads, no barriers
        const int g    = ob >> 1;
        const int half = ob & 1;
        const int jo   = half * 128 + wave * 16;  // out cols [jo, jo+16)
        floatx4 o4[4] = {};
        #pragma unroll 1
        for (int t = 0; t < SEQ; ++t) {
            // wait phi_t complete from all 16 producer waves of group g
            {
                int guard = 0;
                while (true) {
                    const bool nr = (lane < 16) &&
                        (flagld(&pfl[(g * 16 + lane) * 16]) < t + 1);
                    if (__ballot(nr) == 0) break;
                    if (++guard > 65536) break;
                }
            }
            #pragma unroll
            for (int a = 0; a < 4; ++a) o4[a] *= pre[a];
            const __hip_bfloat16* pb =
                phib + ((size_t)(g * RING + (t & (RING - 1))) * 16) * 512;
            #pragma unroll 2
            for (int ks = 0; ks < 16; ++ks) {
                short8 ap;
                ldcc(ap, pb + lrow * 512 + ks * 32 + 8 * quad);
                #pragma unroll
                for (int a = 0; a < 4; ++a) {
                    const short8 bw = ldg8(Wob + (jo + lrow) * 2048 + a * 512
                                               + ks * 32 + 8 * quad);
                    o4[a] = MFMA(ap, bw, o4[a]);
                }
            }
            #pragma unroll
            for (int a = 0; a < 4; ++a) o4[a] *= post[a];
            // all this wave's ring reads for slot t are complete (consumed by MFMA)
            asm volatile("s_waitcnt vmcnt(0)" ::: "memory");
            if (lane == 0) flag_sc1(&ofl[(g * 16 + half * 8 + wave) * 16], t + 1);
        }
        const float bov = bo[jo + lrow];
        #pragma unroll
        for (int i = 0; i < 4; ++i) {
            const int row = g * 16 + quad * 4 + i;
            const float v = o4[0][i] + o4[1][i] + o4[2][i] + o4[3][i] + bov;
            out[row * OUTD + jo + lrow] = fmaxf(v, 0.f);
        }
    }
}

extern "C" void kernel_launch(void* const* d_in, const int* in_sizes, int n_in,
                              void* d_out, int out_size, void* d_ws, size_t ws_size,
                              hipStream_t stream)
{
    const float* x  = (const float*)d_in[0];
    const float* W1 = (const float*)d_in[1];
    const float* b1 = (const float*)d_in[2];
    const float* W2 = (const float*)d_in[3];
    const float* b2 = (const float*)d_in[4];
    const float* Wo = (const float*)d_in[5];
    const float* bo = (const float*)d_in[6];
    float* out = (float*)d_out;
    char* ws = (char*)d_ws;

    constexpr size_t O_CTRL = 0;                                // flags (32 KB)
    constexpr size_t O_PHIB = 32768;                            // 8*16*16*512 bf16 = 2 MB
    constexpr size_t O_W1B  = O_PHIB + 2097152;                 // 1 MB
    constexpr size_t O_W2B  = O_W1B + 1048576;                  // 512 KB
    constexpr size_t O_WOB  = O_W2B + 524288;                   // 1 MB
    constexpr size_t O_XBF  = O_WOB + 1048576;                  // 32 MB
    // total ~36.5 MB

    hipMemsetAsync(ws + O_CTRL, 0, 32768, stream);
    convert_f32_bf16<<<SEQ * BATCH * XD / 1024, 256, 0, stream>>>(
        x, (__hip_bfloat16*)(ws + O_XBF));
    convert_f32_bf16<<<RD * 2048 / 1024, 256, 0, stream>>>(
        W1, (__hip_bfloat16*)(ws + O_W1B));
    convert_f32_bf16<<<PHID * 512 / 1024, 256, 0, stream>>>(
        W2, (__hip_bfloat16*)(ws + O_W2B));
    convert_f32_bf16<<<OUTD * 2048 / 1024, 256, 0, stream>>>(
        Wo, (__hip_bfloat16*)(ws + O_WOB));
    sru_rows<<<NG + NOB, 1024, 0, stream>>>(
        b1, b2, bo,
        (const __hip_bfloat16*)(ws + O_XBF),
        (const __hip_bfloat16*)(ws + O_W1B),
        (const __hip_bfloat16*)(ws + O_W2B),
        (const __hip_bfloat16*)(ws + O_WOB),
        (__hip_bfloat16*)(ws + O_PHIB),
        out, (int*)(ws + O_CTRL));
}

// Round 12
// 8553.171 us; speedup vs baseline: 2.8714x; 2.8714x over previous
//
#include <hip/hip_runtime.h>
#include <hip/hip_bf16.h>

#define SEQ   512
#define BATCH 128
#define XD    256
#define PHID  512
#define RD    256
#define OUTD  256
#define NPHI  8
#define NS    16
#define NO    16
#define NBLK  (NPHI + NS + NO)
#define RING  8

typedef __attribute__((ext_vector_type(8))) short short8;
typedef __attribute__((ext_vector_type(4))) float floatx4;
typedef __attribute__((ext_vector_type(4))) unsigned int uint4v;

#define MFMA(a, b, c) __builtin_amdgcn_mfma_f32_16x16x32_bf16((a), (b), (c), 0, 0, 0)

// counted vmem wait + scheduler pin (guide rule #18: sched_barrier keeps uses after)
#define WAITVM(N) do { asm volatile("s_waitcnt vmcnt(" #N ")" ::: "memory"); \
                       __builtin_amdgcn_sched_barrier(0); } while (0)

__device__ inline short8 ldg8(const __hip_bfloat16* p) {
    return *reinterpret_cast<const short8*>(p);
}
// LLC-coherent 16B u32 load (sc1 bypasses possibly-stale per-XCD L2) — verified r2/r4/r6
__device__ inline void ldu4(uint4v& d, const unsigned int* p) {
    asm volatile("global_load_dwordx4 %0, %1, off sc1" : "=v"(d) : "v"(p) : "memory");
}
// LLC write-through 4B store — verified r2/r4/r6
__device__ inline void stu(unsigned int* p, unsigned int v) {
    asm volatile("global_store_dword %0, %1, off sc1" :: "v"(p), "v"(v) : "memory");
}
__device__ inline int flagld(const int* p) {
    return __hip_atomic_load(p, __ATOMIC_RELAXED, __HIP_MEMORY_SCOPE_AGENT);
}
__device__ inline void flag_sc1(int* p, int v) {
    asm volatile("global_store_dword %0, %1, off sc1" :: "v"(p), "v"(v) : "memory");
}
// all 4 words carry tag 'w' in the high 16 bits?
__device__ inline bool tag4(const uint4v q, unsigned int w) {
    return ((q[0] >> 16) == w) & ((q[1] >> 16) == w) &
           ((q[2] >> 16) == w) & ((q[3] >> 16) == w);
}
// pack 8 tagged u32 (bf16 in low16) -> short8 for MFMA
__device__ inline short8 pkt(const uint4v a, const uint4v b) {
    uint4v r;
    r[0] = (a[0] & 0xffffu) | (a[1] << 16);
    r[1] = (a[2] & 0xffffu) | (a[3] << 16);
    r[2] = (b[0] & 0xffffu) | (b[1] << 16);
    r[3] = (b[2] & 0xffffu) | (b[3] << 16);
    return __builtin_bit_cast(short8, r);
}
__device__ inline unsigned int bfb(float v) {
    return (unsigned int)__builtin_bit_cast(unsigned short, __float2bfloat16(v));
}

__global__ void convert_x(const float* __restrict__ x, __hip_bfloat16* __restrict__ xbf) {
    const int gid = blockIdx.x * blockDim.x + threadIdx.x;   // grid covers N/4 exactly
    const float4 v = reinterpret_cast<const float4*>(x)[gid];
    __hip_bfloat16* d = xbf + 4 * (size_t)gid;
    d[0] = __float2bfloat16(v.x); d[1] = __float2bfloat16(v.y);
    d[2] = __float2bfloat16(v.z); d[3] = __float2bfloat16(v.w);
}

// group-g phi read: 16 dwordx4 into Q (4 ki x 2 row-halves x 2)
#define S_ISSUE(Q, g) do { _Pragma("unroll") \
  for (int ki = 0; ki < 4; ++ki) { \
    ldu4(Q[ki*4+0], p0 + (g)*128 + ki*32); \
    ldu4(Q[ki*4+1], p0 + (g)*128 + ki*32 + 4); \
    ldu4(Q[ki*4+2], p1 + (g)*128 + ki*32); \
    ldu4(Q[ki*4+3], p1 + (g)*128 + ki*32 + 4); } } while (0)

#define S_VALID(Q, g) do { int _gd = 0; \
  while (true) { bool _ok = true; \
    _Pragma("unroll") for (int _i = 0; _i < 16; ++_i) _ok &= tag4(Q[_i], want); \
    if (__ballot(!_ok) == 0) break; \
    if (++_gd > 4096) break; \
    S_ISSUE(Q, (g)); WAITVM(0); } } while (0)

#define S_CONS(Q, g) do { _Pragma("unroll") \
  for (int ki = 0; ki < 4; ++ki) { \
    const short8 _a0 = pkt(Q[ki*4+0], Q[ki*4+1]); \
    const short8 _a1 = pkt(Q[ki*4+2], Q[ki*4+3]); \
    const int _k = (g)*128 + ki*32; \
    _Pragma("unroll") for (int a = 0; a < 4; ++a) { \
      const short8 _b = *(const short8*)&wlds[(((a*64 + (_k>>3) + quad)*16 + lrow) << 3)]; \
      s4[a][0] = MFMA(_a0, _b, s4[a][0]); \
      s4[a][1] = MFMA(_a1, _b, s4[a][1]); } } } while (0)

// 40 persistent blocks, wave-decoupled (r6-verified structure).  TAGGED-DATA
// transport: every r/phi word is u32 = (tag<<16)|bf16, tag = t+1.  Consumers
// read data directly and retry until every tag matches — no producer drain, no
// flags, no ordering assumptions (only sc1 eventual visibility, r2/r4/r6).
//   bid  0..7  : phi-blocks — 64 phi cols (W2 64KB LDS); x-part overlaps r-read
//   bid  8..23 : s-blocks   — 16 r cols; s_a in regs
//   bid 24..39 : o-blocks   — 16 out cols; lag via ring + ofl flags (off-path)
__global__ void __launch_bounds__(256) sru_pipe(
    const float* __restrict__ W1, const float* __restrict__ W2,
    const float* __restrict__ Wo,
    const float* __restrict__ b1, const float* __restrict__ b2,
    const float* __restrict__ bo,
    const __hip_bfloat16* __restrict__ xbf,
    unsigned int* __restrict__ rT,      // [128][256] tagged u32
    unsigned int* __restrict__ phiT,    // [RING][128][512] tagged u32
    float* __restrict__ out, int* __restrict__ ctrl)
{
    __shared__ __hip_bfloat16 wlds[32768];   // 64 KB
    const int bid  = blockIdx.x;
    const int tid  = threadIdx.x;
    const int wave = tid >> 6;
    const int lane = tid & 63;
    const int quad = lane >> 4;
    const int lrow = lane & 15;
    const int m0   = wave * 32;              // each wave owns 32 batch rows
    int* ofl = ctrl;                         // (ob*4+w)*16

    if (bid < NPHI) {
        // ================= phi-block (64 cols) =================
        const int j0 = bid * 64;
        for (int i = tid * 4; i < 64 * 512; i += 1024) {
            const int n = i >> 9, k = i & 511;
            const int part = k >> 8, kk = k & 255;
            const float4 v = *reinterpret_cast<const float4*>(&W2[(j0 + n) * 512 + k]);
            __hip_bfloat16* dst = &wlds[(((part * 32 + (kk >> 3)) * 64 + n) << 3) + (kk & 7)];
            dst[0] = __float2bfloat16(v.x); dst[1] = __float2bfloat16(v.y);
            dst[2] = __float2bfloat16(v.z); dst[3] = __float2bfloat16(v.w);
        }
        __syncthreads();                     // weights resident (only barrier)
        float bj[4];
        #pragma unroll
        for (int j2 = 0; j2 < 4; ++j2) bj[j2] = b2[j0 + j2 * 16 + lrow];
        const unsigned int* r0 = rT + (m0 + lrow) * RD + quad * 8;
        const unsigned int* r1 = rT + (m0 + 16 + lrow) * RD + quad * 8;
        #pragma unroll 1
        for (int t = 0; t < SEQ; ++t) {
            const unsigned int want = t + 1;
            floatx4 acc[2][4] = {};
            // x-part (independent of this step's r) — overlaps the r tag-read
            const __hip_bfloat16* xt = xbf + (size_t)(t * BATCH + m0) * XD;
            #pragma unroll
            for (int k = 0; k < XD; k += 32) {
                const short8 a0 = ldg8(xt + lrow * XD + k + 8 * quad);
                const short8 a1 = ldg8(xt + (16 + lrow) * XD + k + 8 * quad);
                #pragma unroll
                for (int j2 = 0; j2 < 4; ++j2) {
                    const short8 b = *(const short8*)&wlds[((((k >> 3) + quad) * 64 + j2 * 16 + lrow) << 3)];
                    acc[0][j2] = MFMA(a0, b, acc[0][j2]);
                    acc[1][j2] = MFMA(a1, b, acc[1][j2]);
                }
            }
            // ring gate on o-progress (off-critical-path; flags, r6-verified)
            { int guard = 0;
              while (true) {
                  const bool nr = (lane < 16) &&
                      (flagld(&ofl[(lane * 4 + wave) * 16]) < t - (RING - 1));
                  if (__ballot(nr) == 0) break;
                  if (++guard > (1 << 15)) break;
              } }
            // ---- r tag-read, half 0 (rows m0..m0+15) ----
            uint4v q[16]; short8 pa[8];
            #pragma unroll
            for (int ks = 0; ks < 8; ++ks) { ldu4(q[2*ks], r0 + ks*32); ldu4(q[2*ks+1], r0 + ks*32 + 4); }
            WAITVM(0);
            { int gd = 0;
              while (true) {
                  bool ok = true;
                  #pragma unroll
                  for (int i = 0; i < 16; ++i) ok &= tag4(q[i], want);
                  if (__ballot(!ok) == 0) break;
                  if (++gd > 4096) break;
                  #pragma unroll
                  for (int ks = 0; ks < 8; ++ks) { ldu4(q[2*ks], r0 + ks*32); ldu4(q[2*ks+1], r0 + ks*32 + 4); }
                  WAITVM(0);
              } }
            #pragma unroll
            for (int ks = 0; ks < 8; ++ks) pa[ks] = pkt(q[2*ks], q[2*ks+1]);
            // issue half 1 while doing half-0 MFMAs (hides load latency)
            #pragma unroll
            for (int ks = 0; ks < 8; ++ks) { ldu4(q[2*ks], r1 + ks*32); ldu4(q[2*ks+1], r1 + ks*32 + 4); }
            #pragma unroll
            for (int ks = 0; ks < 8; ++ks) {
                const int k = ks * 32;
                #pragma unroll
                for (int j2 = 0; j2 < 4; ++j2) {
                    const short8 b = *(const short8*)&wlds[(((32 + (k >> 3) + quad) * 64 + j2 * 16 + lrow) << 3)];
                    acc[0][j2] = MFMA(pa[ks], b, acc[0][j2]);
                }
            }
            WAITVM(0);
            { int gd = 0;
              while (true) {
                  bool ok = true;
                  #pragma unroll
                  for (int i = 0; i < 16; ++i) ok &= tag4(q[i], want);
                  if (__ballot(!ok) == 0) break;
                  if (++gd > 4096) break;
                  #pragma unroll
                  for (int ks = 0; ks < 8; ++ks) { ldu4(q[2*ks], r1 + ks*32); ldu4(q[2*ks+1], r1 + ks*32 + 4); }
                  WAITVM(0);
              } }
            #pragma unroll
            for (int ks = 0; ks < 8; ++ks) pa[ks] = pkt(q[2*ks], q[2*ks+1]);
            #pragma unroll
            for (int ks = 0; ks < 8; ++ks) {
                const int k = ks * 32;
                #pragma unroll
                for (int j2 = 0; j2 < 4; ++j2) {
                    const short8 b = *(const short8*)&wlds[(((32 + (k >> 3) + quad) * 64 + j2 * 16 + lrow) << 3)];
                    acc[1][j2] = MFMA(pa[ks], b, acc[1][j2]);
                }
            }
            // store phi tagged (no drain, no flag — tags are the signal)
            unsigned int* ps = phiT + (size_t)(t & (RING - 1)) * BATCH * PHID;
            #pragma unroll
            for (int h = 0; h < 2; ++h)
                #pragma unroll
                for (int j2 = 0; j2 < 4; ++j2)
                    #pragma unroll
                    for (int i = 0; i < 4; ++i) {
                        const int row = m0 + 16 * h + quad * 4 + i;
                        const float v = acc[h][j2][i] + bj[j2];
                        stu(ps + row * PHID + j0 + j2 * 16 + lrow,
                            (want << 16) | bfb(fmaxf(v, 0.f)));
                    }
        }
    } else if (bid < NPHI + NS) {
        // ================= s-block =================
        const int sb = bid - NPHI, j0 = sb * 16;
        for (int i = tid * 4; i < 4 * 16 * 512; i += 1024) {
            const int a = i >> 13, rem = i & 8191;
            const int n = rem >> 9, k = rem & 511;
            const float4 v = *reinterpret_cast<const float4*>(&W1[(j0 + n) * 2048 + a * 512 + k]);
            __hip_bfloat16* dst = &wlds[(((a * 64 + (k >> 3)) * 16 + n) << 3) + (k & 7)];
            dst[0] = __float2bfloat16(v.x); dst[1] = __float2bfloat16(v.y);
            dst[2] = __float2bfloat16(v.z); dst[3] = __float2bfloat16(v.w);
        }
        __syncthreads();
        const float bjv = b1[j0 + lrow];
        const float pre[4]  = {0.f, 1.f, 9.f, 99.f};    // alpha/(1-alpha)
        const float post[4] = {1.f, 0.5f, 0.1f, 0.01f}; // (1-alpha)
        floatx4 s4[4][2] = {};
        #pragma unroll 1
        for (int t = 0; t < SEQ; ++t) {
            const unsigned int want = t + 1;
            // emit r_t tagged (no drain, no flag)
            #pragma unroll
            for (int h = 0; h < 2; ++h)
                #pragma unroll
                for (int i = 0; i < 4; ++i) {
                    const int row = m0 + 16 * h + quad * 4 + i;
                    const float rv = s4[0][h][i] + s4[1][h][i] + s4[2][h][i] + s4[3][h][i] + bjv;
                    stu(rT + row * RD + j0 + lrow, (want << 16) | bfb(fmaxf(rv, 0.f)));
                }
            if (t == SEQ - 1) break;
            #pragma unroll
            for (int a = 0; a < 4; ++a)
                #pragma unroll
                for (int h = 0; h < 2; ++h)
                    s4[a][h] *= pre[a];
            const unsigned int* pb = phiT + (size_t)(t & (RING - 1)) * BATCH * PHID;
            const unsigned int* p0 = pb + (m0 + lrow) * PHID + quad * 8;
            const unsigned int* p1 = pb + (m0 + 16 + lrow) * PHID + quad * 8;
            uint4v qa[16], qb[16];
            S_ISSUE(qa, 0);
            S_ISSUE(qb, 1);
            WAITVM(16); S_VALID(qa, 0); S_CONS(qa, 0);
            S_ISSUE(qa, 2);
            WAITVM(16); S_VALID(qb, 1); S_CONS(qb, 1);
            S_ISSUE(qb, 3);
            WAITVM(16); S_VALID(qa, 2); S_CONS(qa, 2);
            WAITVM(0);  S_VALID(qb, 3); S_CONS(qb, 3);
            #pragma unroll
            for (int a = 0; a < 4; ++a)
                #pragma unroll
                for (int h = 0; h < 2; ++h)
                    s4[a][h] *= post[a];
        }
    } else {
        // ================= o-block =================
        const int ob = bid - NPHI - NS, j0 = ob * 16;
        for (int i = tid * 4; i < 4 * 16 * 512; i += 1024) {
            const int a = i >> 13, rem = i & 8191;
            const int n = rem >> 9, k = rem & 511;
            const float4 v = *reinterpret_cast<const float4*>(&Wo[(j0 + n) * 2048 + a * 512 + k]);
            __hip_bfloat16* dst = &wlds[(((a * 64 + (k >> 3)) * 16 + n) << 3) + (k & 7)];
            dst[0] = __float2bfloat16(v.x); dst[1] = __float2bfloat16(v.y);
            dst[2] = __float2bfloat16(v.z); dst[3] = __float2bfloat16(v.w);
        }
        __syncthreads();
        const float pre[4]  = {0.f, 1.f, 9.f, 99.f};
        const float post[4] = {1.f, 0.5f, 0.1f, 0.01f};
        floatx4 s4[4][2] = {};                 // o accumulators (name shared w/ S_CONS)
        #pragma unroll 1
        for (int t = 0; t < SEQ; ++t) {
            const unsigned int want = t + 1;
            #pragma unroll
            for (int a = 0; a < 4; ++a)
                #pragma unroll
                for (int h = 0; h < 2; ++h)
                    s4[a][h] *= pre[a];
            const unsigned int* pb = phiT + (size_t)(t & (RING - 1)) * BATCH * PHID;
            const unsigned int* p0 = pb + (m0 + lrow) * PHID + quad * 8;
            const unsigned int* p1 = pb + (m0 + 16 + lrow) * PHID + quad * 8;
            uint4v qa[16], qb[16];
            S_ISSUE(qa, 0);
            S_ISSUE(qb, 1);
            WAITVM(16); S_VALID(qa, 0); S_CONS(qa, 0);
            S_ISSUE(qa, 2);
            WAITVM(16); S_VALID(qb, 1); S_CONS(qb, 1);
            S_ISSUE(qb, 3);
            WAITVM(16); S_VALID(qa, 2); S_CONS(qa, 2);
            WAITVM(0);  S_VALID(qb, 3); S_CONS(qb, 3);
            #pragma unroll
            for (int a = 0; a < 4; ++a)
                #pragma unroll
                for (int h = 0; h < 2; ++h)
                    s4[a][h] *= post[a];
            // loads fully retired (WAITVM(0) above) -> safe to release ring slot
            if (lane == 0) flag_sc1(&ofl[(ob * 4 + wave) * 16], t + 1);
        }
        const float bjo = bo[j0 + lrow];
        #pragma unroll
        for (int h = 0; h < 2; ++h)
            #pragma unroll
            for (int i = 0; i < 4; ++i) {
                const int row = m0 + 16 * h + quad * 4 + i;
                const float v = s4[0][h][i] + s4[1][h][i] + s4[2][h][i] + s4[3][h][i] + bjo;
                out[row * OUTD + j0 + lrow] = fmaxf(v, 0.f);
            }
    }
}

extern "C" void kernel_launch(void* const* d_in, const int* in_sizes, int n_in,
                              void* d_out, int out_size, void* d_ws, size_t ws_size,
                              hipStream_t stream)
{
    const float* x  = (const float*)d_in[0];
    const float* W1 = (const float*)d_in[1];
    const float* b1 = (const float*)d_in[2];
    const float* W2 = (const float*)d_in[3];
    const float* b2 = (const float*)d_in[4];
    const float* Wo = (const float*)d_in[5];
    const float* bo = (const float*)d_in[6];
    float* out = (float*)d_out;
    char* ws = (char*)d_ws;

    constexpr size_t O_CTRL = 0;                                  // ofl flags (4 KB)
    constexpr size_t O_RT   = 4096;                               // 128x256 u32 = 128 KB
    constexpr size_t O_PHIT = O_RT + 131072;                      // 8x128x512 u32 = 2 MB
    constexpr size_t O_X    = O_PHIT + (size_t)RING * BATCH * PHID * 4;  // bf16 x, 32 MB

    // zero flags + tag buffers (old-run tags would alias new tags at t=511)
    hipMemsetAsync(ws, 0, O_X, stream);
    convert_x<<<SEQ * BATCH * XD / 4 / 256, 256, 0, stream>>>(
        x, (__hip_bfloat16*)(ws + O_X));
    sru_pipe<<<NBLK, 256, 0, stream>>>(
        W1, W2, Wo, b1, b2, bo,
        (const __hip_bfloat16*)(ws + O_X),
        (unsigned int*)(ws + O_RT),
        (unsigned int*)(ws + O_PHIT),
        out, (int*)(ws + O_CTRL));
}

// Round 13
// 4417.985 us; speedup vs baseline: 5.5590x; 1.9360x over previous
//
#include <hip/hip_runtime.h>
#include <hip/hip_bf16.h>

#define SEQ   512
#define BATCH 128
#define XD    256
#define PHID  512
#define RD    256
#define OUTD  256
#define NPHI  8
#define NS    16
#define NO    16
#define NBLK  (NPHI + NS + NO)
#define RING  16

typedef __attribute__((ext_vector_type(8))) short short8;
typedef __attribute__((ext_vector_type(4))) float floatx4;
typedef __attribute__((ext_vector_type(2))) unsigned int uint2v;

#define MFMA(a, b, c) __builtin_amdgcn_mfma_f32_16x16x32_bf16((a), (b), (c), 0, 0, 0)

// counted vmem wait + scheduler pin (guide rule #18)
#define WAITVM(N) do { asm volatile("s_waitcnt vmcnt(" #N ")" ::: "memory"); \
                       __builtin_amdgcn_sched_barrier(0); } while (0)

__device__ inline short8 ldg8(const __hip_bfloat16* p) {
    return *reinterpret_cast<const short8*>(p);
}
// agent-coherent 16B load (sc1, LLC-coherent) — verified r2/r4/r6
__device__ inline void ldcc(short8& d, const __hip_bfloat16* p) {
    asm volatile("global_load_dwordx4 %0, %1, off sc1"
                 : "=v"(d) : "v"(p) : "memory");
}
__device__ inline unsigned int bfb(float v) {
    return (unsigned int)__builtin_bit_cast(unsigned short, __float2bfloat16(v));
}
// coalesced 8B emit: 4 consecutive bf16 cols (operand-swapped C layout), sc1
__device__ inline void st8(__hip_bfloat16* p, float v0, float v1, float v2, float v3) {
    uint2v u;
    u[0] = bfb(v0) | (bfb(v1) << 16);
    u[1] = bfb(v2) | (bfb(v3) << 16);
    asm volatile("global_store_dwordx2 %0, %1, off sc1" :: "v"(p), "v"(u) : "memory");
}
__device__ inline int flagld(const int* p) {
    return __hip_atomic_load(p, __ATOMIC_RELAXED, __HIP_MEMORY_SCOPE_AGENT);
}
// flag post: data stores already drained wave-locally (vmcnt(0)), plain sc1 store
__device__ inline void flag_sc1(int* p, int v) {
    asm volatile("global_store_dword %0, %1, off sc1"
                 :: "v"(p), "v"(v) : "memory");
}

__global__ void convert_x(const float* __restrict__ x, __hip_bfloat16* __restrict__ xbf) {
    const int gid = blockIdx.x * blockDim.x + threadIdx.x;   // grid covers N/4 exactly
    const float4 v = reinterpret_cast<const float4*>(x)[gid];
    __hip_bfloat16* d = xbf + 4 * (size_t)gid;
    d[0] = __float2bfloat16(v.x); d[1] = __float2bfloat16(v.y);
    d[2] = __float2bfloat16(v.z); d[3] = __float2bfloat16(v.w);
}

// 40 persistent blocks, wave-decoupled (r6-verified base, 4219us).  This round:
// OPERAND-SWAPPED MFMA (weights as A, activations as B).  Input fragments are
// bit-identical; the C fragment transposes so each lane holds 4 CONSECUTIVE
// output cols of one row -> phi emit 8x8B dwordx2 (was 32x2B scalar), r emit
// 2x8B (was 8x2B), out float4.  4x fewer LLC store transactions on the
// critical path.  Transport protocol byte-identical to r6.
//   bid  0..7  : phi-blocks — 64 phi cols (W2 64KB LDS); x-part overlaps r-wait
//   bid  8..23 : s-blocks   — 16 r cols; s_a in regs
//   bid 24..39 : o-blocks   — 16 out cols; lag freely (ring 16)
__global__ void __launch_bounds__(256) sru_pipe(
    const float* __restrict__ W1, const float* __restrict__ W2,
    const float* __restrict__ Wo,
    const float* __restrict__ b1, const float* __restrict__ b2,
    const float* __restrict__ bo,
    const __hip_bfloat16* __restrict__ xbf,
    __hip_bfloat16* __restrict__ rbf,
    __hip_bfloat16* __restrict__ phib,
    float* __restrict__ out, int* __restrict__ ctrl)
{
    __shared__ __hip_bfloat16 wlds[32768];   // 64 KB
    const int bid  = blockIdx.x;
    const int tid  = threadIdx.x;
    const int wave = tid >> 6;
    const int lane = tid & 63;
    const int quad = lane >> 4;
    const int lrow = lane & 15;
    const int m0   = wave * 32;              // each wave owns 32 batch rows
    int* rfl = ctrl;                         // (sb*4+w)*16   : 1024 ints
    int* pfl = ctrl + 1024;                  // (p*4+w)*16    : 512 ints
    int* ofl = ctrl + 1536;                  // (ob*4+w)*16   : 1024 ints

    if (bid < NPHI) {
        // ================= phi-block (64 cols) =================
        const int j0 = bid * 64;
        for (int i = tid * 4; i < 64 * 512; i += 1024) {
            const int n = i >> 9, k = i & 511;
            const int part = k >> 8, kk = k & 255;
            const float4 v = *reinterpret_cast<const float4*>(&W2[(j0 + n) * 512 + k]);
            __hip_bfloat16* dst = &wlds[(((part * 32 + (kk >> 3)) * 64 + n) << 3) + (kk & 7)];
            dst[0] = __float2bfloat16(v.x); dst[1] = __float2bfloat16(v.y);
            dst[2] = __float2bfloat16(v.z); dst[3] = __float2bfloat16(v.w);
        }
        __syncthreads();                     // only barrier: weights resident
        float4 bj[4];                        // b2 cols j0 + j2*16 + quad*4 + i
        #pragma unroll
        for (int j2 = 0; j2 < 4; ++j2)
            bj[j2] = *reinterpret_cast<const float4*>(&b2[j0 + j2 * 16 + quad * 4]);
        const __hip_bfloat16* rb0 = rbf + (m0 + lrow) * RD + 8 * quad;
        const __hip_bfloat16* rb1 = rbf + (m0 + 16 + lrow) * RD + 8 * quad;
        #pragma unroll 1
        for (int t = 0; t < SEQ; ++t) {
            floatx4 acc[2][4] = {};
            // x-part (no dependency on this step's r) — overlaps the r-wait below
            const __hip_bfloat16* xt = xbf + (size_t)(t * BATCH + m0) * XD;
            #pragma unroll
            for (int k = 0; k < XD; k += 32) {
                const short8 a0 = ldg8(xt + lrow * XD + k + 8 * quad);
                const short8 a1 = ldg8(xt + (16 + lrow) * XD + k + 8 * quad);
                #pragma unroll
                for (int j2 = 0; j2 < 4; ++j2) {
                    const short8 b = *reinterpret_cast<const short8*>(
                        &wlds[((((k >> 3) + quad) * 64 + j2 * 16 + lrow) << 3)]);
                    acc[0][j2] = MFMA(b, a0, acc[0][j2]);   // swapped: W=A, x=B
                    acc[1][j2] = MFMA(b, a1, acc[1][j2]);
                }
            }
            // per-wave wait: r_t rows m0.. from 16 s-waves; o-gate on ring slot
            {
                int guard = 0;
                while (true) {
                    bool nr = false;
                    if (lane < 16)      nr = flagld(&rfl[(lane * 4 + wave) * 16]) < t + 1;
                    else if (lane < 32) nr = flagld(&ofl[((lane - 16) * 4 + wave) * 16]) < t - (RING - 1);
                    if (__ballot(nr) == 0) break;
                    if (++guard > (1 << 15)) break;     // hang-proofing
                }
            }
            // r-part: LLC loads, double-buffered counted-vmcnt batches
            short8 ra[2][4][2];
            #pragma unroll
            for (int ki = 0; ki < 4; ++ki) {
                ldcc(ra[0][ki][0], rb0 + ki * 32);
                ldcc(ra[0][ki][1], rb1 + ki * 32);
            }
            #pragma unroll
            for (int g = 0; g < 2; ++g) {
                if (g == 0) {
                    #pragma unroll
                    for (int ki = 0; ki < 4; ++ki) {
                        ldcc(ra[1][ki][0], rb0 + 128 + ki * 32);
                        ldcc(ra[1][ki][1], rb1 + 128 + ki * 32);
                    }
                    WAITVM(8);
                } else {
                    WAITVM(0);
                }
                #pragma unroll
                for (int ki = 0; ki < 4; ++ki) {
                    const int k = g * 128 + ki * 32;
                    #pragma unroll
                    for (int j2 = 0; j2 < 4; ++j2) {
                        const short8 b = *reinterpret_cast<const short8*>(
                            &wlds[(((32 + (k >> 3) + quad) * 64 + j2 * 16 + lrow) << 3)]);
                        acc[0][j2] = MFMA(b, ra[g][ki][0], acc[0][j2]);
                        acc[1][j2] = MFMA(b, ra[g][ki][1], acc[1][j2]);
                    }
                }
            }
            // coalesced emit: row = m0+16h+lrow, cols j0 + j2*16 + quad*4 + [0,4)
            __hip_bfloat16* pb = phib + (size_t)(t & (RING - 1)) * BATCH * PHID;
            #pragma unroll
            for (int h = 0; h < 2; ++h) {
                const int row = m0 + 16 * h + lrow;
                #pragma unroll
                for (int j2 = 0; j2 < 4; ++j2)
                    st8(pb + row * PHID + j0 + j2 * 16 + quad * 4,
                        fmaxf(acc[h][j2][0] + bj[j2].x, 0.f),
                        fmaxf(acc[h][j2][1] + bj[j2].y, 0.f),
                        fmaxf(acc[h][j2][2] + bj[j2].z, 0.f),
                        fmaxf(acc[h][j2][3] + bj[j2].w, 0.f));
            }
            asm volatile("s_waitcnt vmcnt(0)" ::: "memory");   // wave's stores at LLC
            if (lane == 0) flag_sc1(&pfl[(bid * 4 + wave) * 16], t + 1);
        }
    } else if (bid < NPHI + NS) {
        // ================= s-block =================
        const int sb = bid - NPHI, j0 = sb * 16;
        for (int i = tid * 4; i < 4 * 16 * 512; i += 1024) {
            const int a = i >> 13, rem = i & 8191;
            const int n = rem >> 9, k = rem & 511;
            const float4 v = *reinterpret_cast<const float4*>(
                &W1[(j0 + n) * 2048 + a * 512 + k]);
            __hip_bfloat16* dst = &wlds[(((a * 64 + (k >> 3)) * 16 + n) << 3) + (k & 7)];
            dst[0] = __float2bfloat16(v.x); dst[1] = __float2bfloat16(v.y);
            dst[2] = __float2bfloat16(v.z); dst[3] = __float2bfloat16(v.w);
        }
        __syncthreads();
        const float4 b1v = *reinterpret_cast<const float4*>(&b1[j0 + quad * 4]);
        const float pre[4]  = {0.f, 1.f, 9.f, 99.f};    // alpha/(1-alpha)
        const float post[4] = {1.f, 0.5f, 0.1f, 0.01f}; // (1-alpha)
        floatx4 s[4][2] = {};
        #pragma unroll 1
        for (int t = 0; t < SEQ; ++t) {
            // emit r_t: row = m0+16h+lrow, cols j0 + quad*4 + [0,4) — 8B each
            #pragma unroll
            for (int h = 0; h < 2; ++h) {
                const int row = m0 + 16 * h + lrow;
                st8(rbf + row * RD + j0 + quad * 4,
                    fmaxf(s[0][h][0] + s[1][h][0] + s[2][h][0] + s[3][h][0] + b1v.x, 0.f),
                    fmaxf(s[0][h][1] + s[1][h][1] + s[2][h][1] + s[3][h][1] + b1v.y, 0.f),
                    fmaxf(s[0][h][2] + s[1][h][2] + s[2][h][2] + s[3][h][2] + b1v.z, 0.f),
                    fmaxf(s[0][h][3] + s[1][h][3] + s[2][h][3] + s[3][h][3] + b1v.w, 0.f));
            }
            asm volatile("s_waitcnt vmcnt(0)" ::: "memory");
            if (lane == 0) flag_sc1(&rfl[(sb * 4 + wave) * 16], t + 1);
            if (t == SEQ - 1) break;
            // wait phi_t rows m0.. from the 8 phi-waves
            {
                int guard = 0;
                while (true) {
                    bool nr = false;
                    if (lane < 8) nr = flagld(&pfl[(lane * 4 + wave) * 16]) < t + 1;
                    if (__ballot(nr) == 0) break;
                    if (++guard > (1 << 15)) break;
                }
            }
            #pragma unroll
            for (int a = 0; a < 4; ++a)
                #pragma unroll
                for (int h = 0; h < 2; ++h)
                    s[a][h] *= pre[a];
            const __hip_bfloat16* pb = phib + (size_t)(t & (RING - 1)) * BATCH * PHID;
            const __hip_bfloat16* pb0 = pb + (m0 + lrow) * PHID + 8 * quad;
            const __hip_bfloat16* pb1 = pb + (m0 + 16 + lrow) * PHID + 8 * quad;
            short8 fa[2][4][2];
            #pragma unroll
            for (int ki = 0; ki < 4; ++ki) {
                ldcc(fa[0][ki][0], pb0 + ki * 32);
                ldcc(fa[0][ki][1], pb1 + ki * 32);
            }
            #pragma unroll
            for (int g = 0; g < 4; ++g) {
                if (g < 3) {
                    #pragma unroll
                    for (int ki = 0; ki < 4; ++ki) {
                        ldcc(fa[(g + 1) & 1][ki][0], pb0 + (g + 1) * 128 + ki * 32);
                        ldcc(fa[(g + 1) & 1][ki][1], pb1 + (g + 1) * 128 + ki * 32);
                    }
                    WAITVM(8);
                } else {
                    WAITVM(0);
                }
                #pragma unroll
                for (int ki = 0; ki < 4; ++ki) {
                    const int k = g * 128 + ki * 32;
                    #pragma unroll
                    for (int a = 0; a < 4; ++a) {
                        const short8 b = *reinterpret_cast<const short8*>(
                            &wlds[(((a * 64 + (k >> 3) + quad) * 16 + lrow) << 3)]);
                        s[a][0] = MFMA(b, fa[g & 1][ki][0], s[a][0]);   // swapped
                        s[a][1] = MFMA(b, fa[g & 1][ki][1], s[a][1]);
                    }
                }
            }
            #pragma unroll
            for (int a = 0; a < 4; ++a)
                #pragma unroll
                for (int h = 0; h < 2; ++h)
                    s[a][h] *= post[a];
        }
    } else {
        // ================= o-block =================
        const int ob = bid - NPHI - NS, j0 = ob * 16;
        for (int i = tid * 4; i < 4 * 16 * 512; i += 1024) {
            const int a = i >> 13, rem = i & 8191;
            const int n = rem >> 9, k = rem & 511;
            const float4 v = *reinterpret_cast<const float4*>(
                &Wo[(j0 + n) * 2048 + a * 512 + k]);
            __hip_bfloat16* dst = &wlds[(((a * 64 + (k >> 3)) * 16 + n) << 3) + (k & 7)];
            dst[0] = __float2bfloat16(v.x); dst[1] = __float2bfloat16(v.y);
            dst[2] = __float2bfloat16(v.z); dst[3] = __float2bfloat16(v.w);
        }
        __syncthreads();
        const float pre[4]  = {0.f, 1.f, 9.f, 99.f};
        const float post[4] = {1.f, 0.5f, 0.1f, 0.01f};
        floatx4 o[4][2] = {};
        #pragma unroll 1
        for (int t = 0; t < SEQ; ++t) {
            {
                int guard = 0;
                while (true) {
                    bool nr = false;
                    if (lane < 8) nr = flagld(&pfl[(lane * 4 + wave) * 16]) < t + 1;
                    if (__ballot(nr) == 0) break;
                    if (++guard > (1 << 15)) break;
                }
            }
            #pragma unroll
            for (int a = 0; a < 4; ++a)
                #pragma unroll
                for (int h = 0; h < 2; ++h)
                    o[a][h] *= pre[a];
            const __hip_bfloat16* pb = phib + (size_t)(t & (RING - 1)) * BATCH * PHID;
            const __hip_bfloat16* pb0 = pb + (m0 + lrow) * PHID + 8 * quad;
            const __hip_bfloat16* pb1 = pb + (m0 + 16 + lrow) * PHID + 8 * quad;
            short8 fa[2][4][2];
            #pragma unroll
            for (int ki = 0; ki < 4; ++ki) {
                ldcc(fa[0][ki][0], pb0 + ki * 32);
                ldcc(fa[0][ki][1], pb1 + ki * 32);
            }
            #pragma unroll
            for (int g = 0; g < 4; ++g) {
                if (g < 3) {
                    #pragma unroll
                    for (int ki = 0; ki < 4; ++ki) {
                        ldcc(fa[(g + 1) & 1][ki][0], pb0 + (g + 1) * 128 + ki * 32);
                        ldcc(fa[(g + 1) & 1][ki][1], pb1 + (g + 1) * 128 + ki * 32);
                    }
                    WAITVM(8);
                } else {
                    WAITVM(0);
                }
                #pragma unroll
                for (int ki = 0; ki < 4; ++ki) {
                    const int k = g * 128 + ki * 32;
                    #pragma unroll
                    for (int a = 0; a < 4; ++a) {
                        const short8 b = *reinterpret_cast<const short8*>(
                            &wlds[(((a * 64 + (k >> 3) + quad) * 16 + lrow) << 3)]);
                        o[a][0] = MFMA(b, fa[g & 1][ki][0], o[a][0]);   // swapped
                        o[a][1] = MFMA(b, fa[g & 1][ki][1], o[a][1]);
                    }
                }
            }
            #pragma unroll
            for (int a = 0; a < 4; ++a)
                #pragma unroll
                for (int h = 0; h < 2; ++h)
                    o[a][h] *= post[a];
            // WAITVM(0) above: this wave's phi loads complete -> safe to release slot
            if (lane == 0) flag_sc1(&ofl[(ob * 4 + wave) * 16], t + 1);
        }
        // coalesced final write: row = m0+16h+lrow, cols jo + quad*4 + [0,4)
        const float4 bov = *reinterpret_cast<const float4*>(&bo[j0 + quad * 4]);
        #pragma unroll
        for (int h = 0; h < 2; ++h) {
            const int row = m0 + 16 * h + lrow;
            float4 v;
            v.x = fmaxf(o[0][h][0] + o[1][h][0] + o[2][h][0] + o[3][h][0] + bov.x, 0.f);
            v.y = fmaxf(o[0][h][1] + o[1][h][1] + o[2][h][1] + o[3][h][1] + bov.y, 0.f);
            v.z = fmaxf(o[0][h][2] + o[1][h][2] + o[2][h][2] + o[3][h][2] + bov.z, 0.f);
            v.w = fmaxf(o[0][h][3] + o[1][h][3] + o[2][h][3] + o[3][h][3] + bov.w, 0.f);
            *reinterpret_cast<float4*>(&out[row * OUTD + j0 + quad * 4]) = v;
        }
    }
}

extern "C" void kernel_launch(void* const* d_in, const int* in_sizes, int n_in,
                              void* d_out, int out_size, void* d_ws, size_t ws_size,
                              hipStream_t stream)
{
    const float* x  = (const float*)d_in[0];
    const float* W1 = (const float*)d_in[1];
    const float* b1 = (const float*)d_in[2];
    const float* W2 = (const float*)d_in[3];
    const float* b2 = (const float*)d_in[4];
    const float* Wo = (const float*)d_in[5];
    const float* bo = (const float*)d_in[6];
    float* out = (float*)d_out;
    char* ws = (char*)d_ws;

    constexpr size_t O_CTRL = 0;                                  // 2560 ints (per-wave flags)
    constexpr size_t O_RBF  = 16384;                              // 128x256 bf16 = 64 KB
    constexpr size_t O_PHI  = O_RBF + (size_t)BATCH * RD * 2;     // 16 x 128x512 bf16 = 2 MB
    constexpr size_t O_X    = O_PHI + (size_t)RING * BATCH * PHID * 2;  // 32 MB

    hipMemsetAsync(ws + O_CTRL, 0, 12288, stream);
    convert_x<<<SEQ * BATCH * XD / 4 / 256, 256, 0, stream>>>(
        x, (__hip_bfloat16*)(ws + O_X));
    sru_pipe<<<NBLK, 256, 0, stream>>>(
        W1, W2, Wo, b1, b2, bo,
        (const __hip_bfloat16*)(ws + O_X),
        (__hip_bfloat16*)(ws + O_RBF),
        (__hip_bfloat16*)(ws + O_PHI),
        out, (int*)(ws + O_CTRL));
}